// Round 9
// baseline (166.743 us; speedup 1.0000x reference)
//
#include <hip/hip_runtime.h>

// SkeletonConv: out[b,o,h,w] = sum_{c,k} W[o,c,k] * x[b,c, h+(k-1)*step, w+(k-1)*dil]
// B=64, C_in=C_out=16, K=3, H=W=256, fp32.
// R9: transposed assignment — one thread = one PIXEL (all 16 c in, 16 o out).
//     acc = 16 VGPRs (vs R7's 64) -> ~56 VGPR total -> 8 waves/SIMD (hw max).
//     Block = one (b,h) row: h,b from blockIdx ONLY -> x-row base is block-uniform
//     (s[base] + loop-invariant lane voffsets wl/w/wr; per-c advance on scalar pipe).
//     Taps = 3 direct dword loads/c (coalesced, +-1 overlap = L1 hits): no shfl, no LDS.
//     Chunk-4 c-pipeline as in R7.
//     Ledger: R1 157 / R2 2660 spill / R3 272 / R4 477 regblow / R5 387 LDS /
//     R6 148 AGPR-shuttle / R7 114.7 best / R8 127.9 (pk_fma NOT 2x on SIMD-32).

constexpr int CIN = 16, COUT = 16, KK = 3, H = 256, W = 256;
constexpr int CHUNK = 4;          // c-channels per pipeline stage

__global__ __launch_bounds__(256, 6)   // cap 85; expected alloc ~56 -> 8 waves/SIMD
void skel_conv_kernel(const float* __restrict__ x, const float* __restrict__ wgt,
                      const int* __restrict__ dil_p, const int* __restrict__ step_p,
                      float* __restrict__ out, int B)
{
    const int dil  = dil_p[0];
    const int step = step_p[0];

    const int w = threadIdx.x;             // lane-contiguous w; block = one (b,h) row
    const int h = blockIdx.x & (H - 1);    // uniform per block (provably, from blockIdx)
    const int b = blockIdx.x >> 8;
    if (b >= B) return;
    const size_t cs = (size_t)H * W;

    float acc[COUT];
    #pragma unroll
    for (int o = 0; o < COUT; ++o) acc[o] = 0.f;

    if (dil == 1 && step == 0) {
        const float* xb = x + (size_t)b * CIN * cs + (size_t)h * W;  // block-uniform base
        const int  wl = (w == 0)     ? 0     : w - 1;   // loop-invariant lane offsets
        const int  wr = (w == W - 1) ? W - 1 : w + 1;
        const bool eL = (w == 0), eR = (w == W - 1);

        float pl[CHUNK], pm[CHUNK], pr[CHUNK];          // chunk in flight
        #pragma unroll
        for (int i = 0; i < CHUNK; ++i) {               // prologue: chunk 0
            const float* pc = xb + (size_t)i * cs;
            pl[i] = pc[wl]; pm[i] = pc[w]; pr[i] = pc[wr];
        }

        #pragma unroll 1
        for (int cc = 0; cc < CIN; cc += CHUNK) {
            // issue next chunk's 12 independent loads (last iter re-reads, L1 hit)
            const int nb = (cc + CHUNK < CIN) ? cc + CHUNK : cc;
            float vl[CHUNK], vm[CHUNK], vr[CHUNK];
            #pragma unroll
            for (int i = 0; i < CHUNK; ++i) {
                const float* pc = xb + (size_t)(nb + i) * cs;
                vl[i] = pc[wl]; vm[i] = pc[w]; vr[i] = pc[wr];
            }

            // compute current chunk: 4 c x 16 o x 3 k = 192 FMA
            #pragma unroll
            for (int i = 0; i < CHUNK; ++i) {
                const int c = cc + i;
                const float l = eL ? 0.f : pl[i];       // zero padding at w edges
                const float m = pm[i];
                const float r = eR ? 0.f : pr[i];
                #pragma unroll
                for (int o = 0; o < COUT; ++o) {
                    const float* wq = wgt + ((size_t)o * CIN + c) * KK;  // uniform -> s_load
                    acc[o] = fmaf(wq[0], l, acc[o]);
                    acc[o] = fmaf(wq[1], m, acc[o]);
                    acc[o] = fmaf(wq[2], r, acc[o]);
                }
            }
            #pragma unroll
            for (int i = 0; i < CHUNK; ++i) { pl[i] = vl[i]; pm[i] = vm[i]; pr[i] = vr[i]; }
        }
    } else {
        // Generic path: clamped loads + select (never faults, any dil/step).
        #pragma unroll 1
        for (int c = 0; c < CIN; ++c) {
            const float* xc = x + (size_t)b * CIN * cs + (size_t)c * cs;
            #pragma unroll
            for (int k = 0; k < KK; ++k) {
                const int off = k - KK / 2;
                const int hh  = h + off * step;
                const int ww  = w + off * dil;
                const bool ok = (hh >= 0) && (hh < H) && (ww >= 0) && (ww < W);
                const int hcl = hh < 0 ? 0 : (hh > H - 1 ? H - 1 : hh);
                const int wcl = ww < 0 ? 0 : (ww > W - 1 ? W - 1 : ww);
                float v = xc[(size_t)hcl * W + wcl];
                v = ok ? v : 0.f;
                #pragma unroll
                for (int o = 0; o < COUT; ++o)
                    acc[o] = fmaf(wgt[((size_t)o * CIN + c) * KK + k], v, acc[o]);
            }
        }
    }

    // store: per o, 64 lanes x 4B contiguous -> coalesced; base advance is scalar
    float* op = out + (size_t)b * COUT * cs + (size_t)h * W + w;
    #pragma unroll
    for (int o = 0; o < COUT; ++o)
        op[(size_t)o * cs] = acc[o];
}

extern "C" void kernel_launch(void* const* d_in, const int* in_sizes, int n_in,
                              void* d_out, int out_size, void* d_ws, size_t ws_size,
                              hipStream_t stream) {
    const float* x    = (const float*)d_in[0];
    const float* wgt  = (const float*)d_in[1];
    const int*   dil  = (const int*)d_in[2];
    const int*   step = (const int*)d_in[3];
    float*       out  = (float*)d_out;

    const int B = in_sizes[0] / (CIN * H * W);
    const int grid = B * H;                    // one block per (b,h) row
    skel_conv_kernel<<<grid, 256, 0, stream>>>(x, wgt, dil, step, out, B);
}